// Round 1
// baseline (186.219 us; speedup 1.0000x reference)
//
#include <hip/hip_runtime.h>
#include <math.h>

#define BB   1024
#define MM   32
#define HH   2
#define DD   64
#define NREL 32
#define TPB  256

// LDS row strides padded to 65 floats: odd stride => bank (row+col)%32 spreads
// fully, making both access orientations (fixed-col varying-row and
// fixed-row varying-col) conflict-free (2 lanes/bank is free on gfx950).
#define HS 65
#define QS 65

__global__ __launch_bounds__(TPB) void ripple_fused(
    const int* __restrict__ edge_index,     // (B,2)
    const int* __restrict__ ripple_sets,    // (H,B,M,2)
    const float* __restrict__ entity_emb,   // (N_ENT, D)
    const float* __restrict__ relation_emb, // (NREL, D*D)
    float* __restrict__ out)                // (B,1)
{
    __shared__ float item_s[DD];
    __shared__ float h_s[HH * MM * HS];   // 64 rows x 65  (~16.3 KB)
    __shared__ float q_s[NREL * QS];      // 32 rows x 65  (~8.2 KB)
    __shared__ int   head_s[HH * MM];
    __shared__ int   rel_s[HH * MM];
    __shared__ float v_s[HH * MM];
    __shared__ float p_s[HH * MM];

    const int b   = blockIdx.x;
    const int tid = threadIdx.x;

    // --- stage item vector and ripple-set indices ---
    if (tid < DD) {
        int item_idx = edge_index[2 * b + 1];          // broadcast load
        item_s[tid] = entity_emb[(size_t)item_idx * DD + tid];
    }
    if (tid < HH * MM) {
        int hop = tid >> 5, m = tid & 31;
        size_t base = ((size_t)(hop * BB + b) * MM + m) * 2;
        head_s[tid] = ripple_sets[base];
        rel_s[tid]  = ripple_sets[base + 1];
    }
    __syncthreads();

    // --- gather h rows: 64 rows x 16 float4 = 1024 float4, 4 per thread ---
    for (int k = 0; k < 4; ++k) {
        int idx = tid + TPB * k;     // 0..1023
        int row = idx >> 4;          // 0..63  (hop*32+m)
        int c4  = idx & 15;          // 0..15
        const float4 v = *(const float4*)(entity_emb + (size_t)head_s[row] * DD + c4 * 4);
        float* dst = h_s + row * HS + c4 * 4;
        dst[0] = v.x; dst[1] = v.y; dst[2] = v.z; dst[3] = v.w;
    }

    // --- q_r = item^T R_r for all 32 relations: 512 (r,c4) tasks, 2/thread ---
    for (int k = 0; k < 2; ++k) {
        int task = tid + TPB * k;    // 0..511
        int r  = task >> 4;
        int c4 = task & 15;
        const float* Rp = relation_emb + (size_t)r * DD * DD + c4 * 4;
        float4 acc = {0.f, 0.f, 0.f, 0.f};
        #pragma unroll
        for (int i = 0; i < DD; ++i) {
            float it = item_s[i];
            const float4 rv = *(const float4*)(Rp + i * DD);
            acc.x += it * rv.x; acc.y += it * rv.y;
            acc.z += it * rv.z; acc.w += it * rv.w;
        }
        float* dst = q_s + r * QS + c4 * 4;
        dst[0] = acc.x; dst[1] = acc.y; dst[2] = acc.z; dst[3] = acc.w;
    }
    __syncthreads();

    // --- vRh[t] = dot(q[rel[t]], h[t])  (wave 0, one lane per t) ---
    if (tid < HH * MM) {
        int r = rel_s[tid];
        const float* qp = q_s + r * QS;
        const float* hp = h_s + tid * HS;
        float acc = 0.f;
        #pragma unroll
        for (int j = 0; j < DD; ++j) acc += qp[j] * hp[j];
        v_s[tid] = acc;
    }
    __syncthreads();

    // --- softmax over m per hop (2 serial threads; 32 values each) ---
    if (tid < HH) {
        const float* vv = v_s + tid * MM;
        float* pp = p_s + tid * MM;
        float mx = vv[0];
        for (int m = 1; m < MM; ++m) mx = fmaxf(mx, vv[m]);
        float s = 0.f;
        for (int m = 0; m < MM; ++m) { float e = expf(vv[m] - mx); pp[m] = e; s += e; }
        float inv = 1.f / s;
        for (int m = 0; m < MM; ++m) pp[m] *= inv;
    }
    __syncthreads();

    // --- u_d = sum_t p[t]*h[t][d];  out[b] = dot(u, item)  (wave 0) ---
    if (tid < DD) {
        float u = 0.f;
        #pragma unroll
        for (int t = 0; t < HH * MM; ++t) u += p_s[t] * h_s[t * HS + tid];
        float prod = u * item_s[tid];
        #pragma unroll
        for (int off = 32; off > 0; off >>= 1) prod += __shfl_down(prod, off, 64);
        if (tid == 0) out[b] = prod;
    }
}

extern "C" void kernel_launch(void* const* d_in, const int* in_sizes, int n_in,
                              void* d_out, int out_size, void* d_ws, size_t ws_size,
                              hipStream_t stream) {
    const int*   edge_index   = (const int*)d_in[0];
    const int*   ripple_sets  = (const int*)d_in[1];
    const float* entity_emb   = (const float*)d_in[2];
    const float* relation_emb = (const float*)d_in[3];
    float* out = (float*)d_out;
    (void)in_sizes; (void)n_in; (void)out_size; (void)d_ws; (void)ws_size;

    ripple_fused<<<dim3(BB), dim3(TPB), 0, stream>>>(
        edge_index, ripple_sets, entity_emb, relation_emb, out);
}

// Round 2
// 175.247 us; speedup vs baseline: 1.0626x; 1.0626x over previous
//
#include <hip/hip_runtime.h>
#include <math.h>

#define BB   1024
#define MM   32
#define HH   2
#define DD   64
#define NREL 32
#define TBB  32          // b-tile per block in kernel A

// ---------------- Kernel A: Q[b][r][j] = sum_i item[b][i] * R[r][i][j] -----
// grid = (BB/TBB, NREL), block = 256
__global__ __launch_bounds__(256) void compute_q(
    const int* __restrict__ edge_index,     // (B,2)
    const float* __restrict__ entity_emb,   // (N_ENT, D)
    const float* __restrict__ relation_emb, // (NREL, D*D)
    float* __restrict__ qout)               // (B, NREL, D)
{
    __shared__ float R_s[DD * DD];          // 16 KB, row-major R[i][j]
    // stride 68: 16B-aligned rows AND banks (68*bl+i)%32=(4bl+i)%32 spread
    __shared__ float item_s[TBB * 68];      // ~8.7 KB

    const int r   = blockIdx.y;
    const int b0  = blockIdx.x * TBB;
    const int tid = threadIdx.x;

    // stage R_r: 1024 float4, 4 per thread (coalesced)
    const float4* Rg = (const float4*)(relation_emb + (size_t)r * DD * DD);
    #pragma unroll
    for (int k = 0; k < 4; ++k)
        ((float4*)R_s)[tid + 256 * k] = Rg[tid + 256 * k];

    // stage 32 item rows: 512 float4, 2 per thread
    #pragma unroll
    for (int k = 0; k < 2; ++k) {
        int idx = tid + 256 * k;            // 0..511
        int bl  = idx >> 4;                 // 0..31
        int c4  = idx & 15;                 // 0..15
        int ei  = edge_index[2 * (b0 + bl) + 1];
        ((float4*)(item_s + bl * 68))[c4] =
            *(const float4*)(entity_emb + (size_t)ei * DD + c4 * 4);
    }
    __syncthreads();

    // each thread: j-chunk j4..j4+3 for b-locals bl0 and bl0+16
    const int j4  = (tid & 15) * 4;
    const int bl0 = tid >> 4;               // 0..15
    float4 acc0 = {0.f, 0.f, 0.f, 0.f};
    float4 acc1 = {0.f, 0.f, 0.f, 0.f};
    #pragma unroll 8
    for (int i = 0; i < DD; ++i) {
        const float4 rv = *(const float4*)(R_s + i * DD + j4);  // 2-way max: free
        const float a0 = item_s[bl0 * 68 + i];                  // 4 banks, bcast
        const float a1 = item_s[(bl0 + 16) * 68 + i];
        acc0.x += a0 * rv.x; acc0.y += a0 * rv.y;
        acc0.z += a0 * rv.z; acc0.w += a0 * rv.w;
        acc1.x += a1 * rv.x; acc1.y += a1 * rv.y;
        acc1.z += a1 * rv.z; acc1.w += a1 * rv.w;
    }
    size_t q0 = ((size_t)(b0 + bl0) * NREL + r) * DD + j4;
    size_t q1 = ((size_t)(b0 + bl0 + 16) * NREL + r) * DD + j4;
    *(float4*)(qout + q0) = acc0;
    *(float4*)(qout + q1) = acc1;
}

// ---------------- Kernel B: gather h + Q rows, softmax, combine ------------
// grid = BB, block = 256
#define HS 65   // odd stride: distinct rows -> distinct banks (2-way free)

__global__ __launch_bounds__(256) void ripple_apply(
    const int* __restrict__ edge_index,
    const int* __restrict__ ripple_sets,    // (H,B,M,2)
    const float* __restrict__ entity_emb,
    const float* __restrict__ qg,           // (B, NREL, D)
    float* __restrict__ out)                // (B,1)
{
    __shared__ float item_s[DD];
    __shared__ float h_s[HH * MM * HS];     // 64 x 65
    __shared__ float q_s[HH * MM * HS];     // 64 x 65 (per-t gathered Q row)
    __shared__ int   head_s[HH * MM];
    __shared__ int   rel_s[HH * MM];
    __shared__ float v_s[HH * MM];
    __shared__ float p_s[HH * MM];

    const int b   = blockIdx.x;
    const int tid = threadIdx.x;

    if (tid < DD) {
        int item_idx = edge_index[2 * b + 1];
        item_s[tid] = entity_emb[(size_t)item_idx * DD + tid];
    }
    if (tid < HH * MM) {
        int hop = tid >> 5, m = tid & 31;
        size_t base = ((size_t)(hop * BB + b) * MM + m) * 2;
        head_s[tid] = ripple_sets[base];
        rel_s[tid]  = ripple_sets[base + 1];
    }
    __syncthreads();

    // gather h rows and Q rows: 64 rows x 16 float4 each = 2048 tasks, 8/thread
    #pragma unroll
    for (int k = 0; k < 4; ++k) {
        int idx = tid + 256 * k;            // 0..1023
        int row = idx >> 4;
        int c4  = idx & 15;
        const float4 hv = *(const float4*)(entity_emb + (size_t)head_s[row] * DD + c4 * 4);
        float* hd = h_s + row * HS + c4 * 4;
        hd[0] = hv.x; hd[1] = hv.y; hd[2] = hv.z; hd[3] = hv.w;
        const float4 qv = *(const float4*)(qg + ((size_t)b * NREL + rel_s[row]) * DD + c4 * 4);
        float* qd = q_s + row * HS + c4 * 4;
        qd[0] = qv.x; qd[1] = qv.y; qd[2] = qv.z; qd[3] = qv.w;
    }
    __syncthreads();

    // v[t] = dot(Q_row[t], h[t])  -- one lane per t
    if (tid < HH * MM) {
        const float* qp = q_s + tid * HS;
        const float* hp = h_s + tid * HS;
        float acc = 0.f;
        #pragma unroll
        for (int j = 0; j < DD; ++j) acc += qp[j] * hp[j];
        v_s[tid] = acc;
    }
    __syncthreads();

    // softmax over m per hop
    if (tid < HH) {
        const float* vv = v_s + tid * MM;
        float* pp = p_s + tid * MM;
        float mx = vv[0];
        for (int m = 1; m < MM; ++m) mx = fmaxf(mx, vv[m]);
        float s = 0.f;
        for (int m = 0; m < MM; ++m) { float e = expf(vv[m] - mx); pp[m] = e; s += e; }
        float inv = 1.f / s;
        for (int m = 0; m < MM; ++m) pp[m] *= inv;
    }
    __syncthreads();

    // u_d = sum_t p[t]*h[t][d]; out[b] = dot(u, item)
    if (tid < DD) {
        float u = 0.f;
        #pragma unroll
        for (int t = 0; t < HH * MM; ++t) u += p_s[t] * h_s[t * HS + tid];
        float prod = u * item_s[tid];
        #pragma unroll
        for (int off = 32; off > 0; off >>= 1) prod += __shfl_down(prod, off, 64);
        if (tid == 0) out[b] = prod;
    }
}

extern "C" void kernel_launch(void* const* d_in, const int* in_sizes, int n_in,
                              void* d_out, int out_size, void* d_ws, size_t ws_size,
                              hipStream_t stream) {
    const int*   edge_index   = (const int*)d_in[0];
    const int*   ripple_sets  = (const int*)d_in[1];
    const float* entity_emb   = (const float*)d_in[2];
    const float* relation_emb = (const float*)d_in[3];
    float* out = (float*)d_out;
    float* qbuf = (float*)d_ws;             // B*NREL*D floats = 8 MB
    (void)in_sizes; (void)n_in; (void)out_size; (void)ws_size;

    compute_q<<<dim3(BB / TBB, NREL), dim3(256), 0, stream>>>(
        edge_index, entity_emb, relation_emb, qbuf);
    ripple_apply<<<dim3(BB), dim3(256), 0, stream>>>(
        edge_index, ripple_sets, entity_emb, qbuf, out);
}

// Round 3
// 170.655 us; speedup vs baseline: 1.0912x; 1.0269x over previous
//
#include <hip/hip_runtime.h>
#include <math.h>

#define BB   1024
#define MM   32
#define HH   2
#define DD   64
#define NREL 32
#define TBB  32          // b-tile per block in kernel A

// ---------------- Kernel A: Q[b][r][j] = sum_i item[b][i] * R[r][i][j] -----
// grid = (BB/TBB, NREL), block = 256.  ~2 us, near compute floor.
__global__ __launch_bounds__(256) void compute_q(
    const int* __restrict__ edge_index,     // (B,2)
    const float* __restrict__ entity_emb,   // (N_ENT, D)
    const float* __restrict__ relation_emb, // (NREL, D*D)
    float* __restrict__ qout)               // (B, NREL, D)
{
    __shared__ float R_s[DD * DD];          // 16 KB, row-major R[i][j]
    __shared__ float item_s[TBB * 68];      // stride 68: 16B-aligned, banks spread

    const int r   = blockIdx.y;
    const int b0  = blockIdx.x * TBB;
    const int tid = threadIdx.x;

    // stage R_r: 1024 float4, 4 per thread (coalesced)
    const float4* Rg = (const float4*)(relation_emb + (size_t)r * DD * DD);
    #pragma unroll
    for (int k = 0; k < 4; ++k)
        ((float4*)R_s)[tid + 256 * k] = Rg[tid + 256 * k];

    // stage 32 item rows: 512 float4, 2 per thread
    #pragma unroll
    for (int k = 0; k < 2; ++k) {
        int idx = tid + 256 * k;            // 0..511
        int bl  = idx >> 4;                 // 0..31
        int c4  = idx & 15;                 // 0..15
        int ei  = edge_index[2 * (b0 + bl) + 1];
        ((float4*)(item_s + bl * 68))[c4] =
            *(const float4*)(entity_emb + (size_t)ei * DD + c4 * 4);
    }
    __syncthreads();

    // each thread: j-chunk j4..j4+3 for b-locals bl0 and bl0+16
    const int j4  = (tid & 15) * 4;
    const int bl0 = tid >> 4;               // 0..15
    float4 acc0 = {0.f, 0.f, 0.f, 0.f};
    float4 acc1 = {0.f, 0.f, 0.f, 0.f};
    #pragma unroll 8
    for (int i = 0; i < DD; ++i) {
        const float4 rv = *(const float4*)(R_s + i * DD + j4);
        const float a0 = item_s[bl0 * 68 + i];
        const float a1 = item_s[(bl0 + 16) * 68 + i];
        acc0.x += a0 * rv.x; acc0.y += a0 * rv.y;
        acc0.z += a0 * rv.z; acc0.w += a0 * rv.w;
        acc1.x += a1 * rv.x; acc1.y += a1 * rv.y;
        acc1.z += a1 * rv.z; acc1.w += a1 * rv.w;
    }
    size_t q0 = ((size_t)(b0 + bl0) * NREL + r) * DD + j4;
    size_t q1 = ((size_t)(b0 + bl0 + 16) * NREL + r) * DD + j4;
    *(float4*)(qout + q0) = acc0;
    *(float4*)(qout + q1) = acc1;
}

// ---------------- Kernel B: gather h + Q rows, softmax, combine ------------
// grid = BB, block = 256.  All phases use all 256 threads (or 64 lanes
// with shuffle parallelism); indices loaded straight from global (L2-hot).
#define HS 65   // odd stride: (t+j)%32 spreads banks, <=2-way everywhere (free)

__global__ __launch_bounds__(256) void ripple_apply(
    const int* __restrict__ edge_index,
    const int* __restrict__ ripple_sets,    // (H,B,M,2) int32
    const float* __restrict__ entity_emb,
    const float* __restrict__ qg,           // (B, NREL, D)
    float* __restrict__ out)                // (B,1)
{
    __shared__ float item_s[DD];
    __shared__ float h_s[HH * MM * HS];     // 64 x 65
    __shared__ float q_s[HH * MM * HS];     // 64 x 65
    __shared__ float vp_s[4 * 64];          // v partials (quarter-dots)
    __shared__ float p_s[HH * MM];
    __shared__ float up_s[4 * 68];          // u partials

    const int b   = blockIdx.x;
    const int tid = threadIdx.x;

    if (tid < DD) {
        int item_idx = edge_index[2 * b + 1];       // broadcast, L2-hot
        item_s[tid] = entity_emb[(size_t)item_idx * DD + tid];
    }

    // gather h rows and Q rows: 64 rows x 16 float4 each; indices read
    // directly (16 threads share one row -> broadcast load, 512 KB L2-hot)
    #pragma unroll
    for (int k = 0; k < 4; ++k) {
        int idx = tid + 256 * k;            // 0..1023
        int row = idx >> 4;                 // t: 0..63
        int c4  = idx & 15;
        int hop = row >> 5, m = row & 31;
        size_t ibase = ((size_t)(hop * BB + b) * MM + m) * 2;
        int head = ripple_sets[ibase];
        int rel  = ripple_sets[ibase + 1];
        const float4 hv = *(const float4*)(entity_emb + (size_t)head * DD + c4 * 4);
        float* hd = h_s + row * HS + c4 * 4;
        hd[0] = hv.x; hd[1] = hv.y; hd[2] = hv.z; hd[3] = hv.w;
        const float4 qv = *(const float4*)(qg + ((size_t)b * NREL + rel) * DD + c4 * 4);
        float* qd = q_s + row * HS + c4 * 4;
        qd[0] = qv.x; qd[1] = qv.y; qd[2] = qv.z; qd[3] = qv.w;
    }
    __syncthreads();

    // v[t] = dot(Q_row[t], h[t]) -- split 4 ways: wave w does j-chunk w*16
    {
        int t = tid & 63;
        int q = tid >> 6;                   // 0..3
        const float* qp = q_s + t * HS + q * 16;
        const float* hp = h_s + t * HS + q * 16;
        float acc = 0.f;
        #pragma unroll
        for (int j = 0; j < 16; ++j) acc += qp[j] * hp[j];
        vp_s[q * 64 + t] = acc;
    }
    __syncthreads();

    // lane-parallel softmax: lane t holds v[t]; xor-offsets <=16 stay inside
    // each 32-lane half (= one hop)
    if (tid < HH * MM) {
        float v = vp_s[tid] + vp_s[64 + tid] + vp_s[128 + tid] + vp_s[192 + tid];
        float mx = v;
        #pragma unroll
        for (int off = 16; off > 0; off >>= 1)
            mx = fmaxf(mx, __shfl_xor(mx, off, 64));
        float e = expf(v - mx);
        float s = e;
        #pragma unroll
        for (int off = 16; off > 0; off >>= 1)
            s += __shfl_xor(s, off, 64);
        p_s[tid] = e / s;
    }
    __syncthreads();

    // u_d = sum_t p[t]*h[t][d] -- split 4 ways over t (16 t's per wave)
    {
        int d    = tid & 63;
        int part = tid >> 6;                // 0..3
        float u = 0.f;
        #pragma unroll
        for (int tt = 0; tt < 16; ++tt) {
            int t = part * 16 + tt;
            u += p_s[t] * h_s[t * HS + d];  // p_s broadcast; h_s 2-way
        }
        up_s[part * 68 + d] = u;
    }
    __syncthreads();

    if (tid < DD) {
        float u = up_s[tid] + up_s[68 + tid] + up_s[136 + tid] + up_s[204 + tid];
        float prod = u * item_s[tid];
        #pragma unroll
        for (int off = 32; off > 0; off >>= 1) prod += __shfl_down(prod, off, 64);
        if (tid == 0) out[b] = prod;
    }
}

extern "C" void kernel_launch(void* const* d_in, const int* in_sizes, int n_in,
                              void* d_out, int out_size, void* d_ws, size_t ws_size,
                              hipStream_t stream) {
    const int*   edge_index   = (const int*)d_in[0];
    const int*   ripple_sets  = (const int*)d_in[1];
    const float* entity_emb   = (const float*)d_in[2];
    const float* relation_emb = (const float*)d_in[3];
    float* out = (float*)d_out;
    float* qbuf = (float*)d_ws;             // B*NREL*D floats = 8 MB
    (void)in_sizes; (void)n_in; (void)out_size; (void)ws_size;

    compute_q<<<dim3(BB / TBB, NREL), dim3(256), 0, stream>>>(
        edge_index, entity_emb, relation_emb, qbuf);
    ripple_apply<<<dim3(BB), dim3(256), 0, stream>>>(
        edge_index, ripple_sets, entity_emb, qbuf, out);
}